// Round 11
// baseline (287.094 us; speedup 1.0000x reference)
//
#include <hip/hip_runtime.h>

// Problem constants (fixed by reference): B=2, N=8192, C=80
constexpr int NB = 2;
constexpr int NN = 8192;
constexpr int NC = 80;
constexpr int ROWS = NN + 1;  // mask rows per batch; row NN is an all-zero row

// d_out layout (floats), in reference return order:
// boxes[B,N,4], max_scores[B,N], labels[B,N], keep[B,N], all_scores[B,N,C]
constexpr size_t OFF_BOXES  = 0;
constexpr size_t OFF_SCORES = (size_t)NB * NN * 4;
constexpr size_t OFF_LABELS = OFF_SCORES + (size_t)NB * NN;
constexpr size_t OFF_KEEP   = OFF_LABELS + (size_t)NB * NN;
constexpr size_t OFF_ALL    = OFF_KEEP + (size_t)NB * NN;

// d_ws layout
constexpr size_t WS_KEYS  = 0;                                   // B*N u64
constexpr size_t WS_VBYTE = WS_KEYS + (size_t)NB * NN * 8;       // B*N u8
constexpr size_t WS_ORDER = WS_VBYTE + (size_t)NB * NN;          // B*N i32
constexpr size_t WS_SBOX  = WS_ORDER + (size_t)NB * NN * 4;      // B*N float4
constexpr size_t WS_VBITS = WS_SBOX + (size_t)NB * NN * 16;      // B*128 u64
constexpr size_t WS_MASK  = WS_VBITS + (size_t)NB * 128 * 8;     // B*ROWS*128 u64
constexpr size_t WS_DNM   = WS_MASK + (size_t)NB * ROWS * 128 * 8; // B*128*4*64 u64
constexpr size_t WS_PART  = WS_DNM + (size_t)NB * 128 * 4 * 64 * 8; // B*8*N i32
constexpr size_t WS_TOTAL = WS_PART + (size_t)NB * 8 * NN * 4;
constexpr size_t WS_TOTAL_OLD = WS_PART;
// Sparse-NMS extension: per-row entry lists written directly by build.
constexpr int ROW_CAP = 64;  // entries per row (u16); deg>cap -> dense path
constexpr size_t WS_RDEG = WS_TOTAL;                              // B*N u32
constexpr size_t WS_RENT = WS_RDEG + (size_t)NB * NN * 4;         // B*N*64 u16
constexpr size_t WS_OVF  = WS_RENT + (size_t)NB * NN * ROW_CAP * 2;
constexpr size_t WS_TOTAL_SPARSE = WS_OVF + 64;
constexpr int DNM_WORDS = NB * 128 * 4 * 64;  // 65536
constexpr int NSEG = 8;                       // rank column segments

typedef unsigned long long u64;
typedef __attribute__((ext_vector_type(2))) unsigned long long u64x2;

// lgkmcnt(0)-only barrier: keeps global loads in flight across it.
__device__ inline void lbar() {
  __builtin_amdgcn_s_waitcnt(0xc07f);
  __builtin_amdgcn_s_barrier();
}

__device__ inline u64 readlane64(u64 v, int src) {
  unsigned int lo = (unsigned int)__builtin_amdgcn_readlane((int)(unsigned int)v, src);
  unsigned int hi = (unsigned int)__builtin_amdgcn_readlane((int)(unsigned int)(v >> 32), src);
  return ((u64)hi << 32) | lo;
}

__device__ inline u64 readfirstlane64(u64 v) {
  unsigned int lo = (unsigned int)__builtin_amdgcn_readfirstlane((int)(unsigned int)v);
  unsigned int hi = (unsigned int)__builtin_amdgcn_readfirstlane((int)(unsigned int)(v >> 32));
  return ((u64)hi << 32) | lo;
}

// IoU exactly mirroring the numpy op order; contraction off so f32 rounding
// matches numpy bit-for-bit. Bit-exactly SYMMETRIC in (p,q).
__device__ inline float iou_pair(const float4 p, const float4 q) {
#pragma clang fp contract(off)
  float areaA = (p.z - p.x) * (p.w - p.y);
  float areaB = (q.z - q.x) * (q.w - q.y);
  float ix1 = fmaxf(p.x, q.x);
  float iy1 = fmaxf(p.y, q.y);
  float ix2 = fminf(p.z, q.z);
  float iy2 = fminf(p.w, q.w);
  float inter = fmaxf(ix2 - ix1, 0.0f) * fmaxf(iy2 - iy1, 0.0f);
  float uni = areaA + areaB - inter;
  return inter / fmaxf(uni, 1e-9f);
}

__device__ inline float clip01(float v) { return fminf(fmaxf(v, 0.0f), 1.0f); }

// One wave per (b,n): sigmoid all 80 classes, max/argmax (first-index ties),
// box decode, validity, sort key. Also zero-inits vbits.
__global__ __launch_bounds__(256) void decode_kernel(
    const float* __restrict__ logits, const float4* __restrict__ deltas,
    const float4* __restrict__ anchors, float4* __restrict__ boxes_out,
    float* __restrict__ scores_out, float* __restrict__ labels_out,
    float* __restrict__ all_out, u64* __restrict__ keys,
    unsigned char* __restrict__ vbyte, u64* __restrict__ vbits) {
#pragma clang fp contract(off)
  if (blockIdx.x == 0 && threadIdx.x < NB * 128) vbits[threadIdx.x] = 0ull;
  int wid = (blockIdx.x * 256 + threadIdx.x) >> 6;  // 0 .. B*N-1
  int lane = threadIdx.x & 63;
  int n = wid & (NN - 1);
  size_t base = (size_t)wid * NC;

  float x0 = logits[base + lane];
  float sig0 = 1.0f / (1.0f + expf(-x0));
  all_out[base + lane] = sig0;
  float bs = sig0;
  int bidx = lane;
  if (lane < NC - 64) {
    float x1 = logits[base + 64 + lane];
    float sig1 = 1.0f / (1.0f + expf(-x1));
    all_out[base + 64 + lane] = sig1;
    if (sig1 > bs) { bs = sig1; bidx = lane + 64; }  // tie -> smaller idx wins
  }
  for (int off = 32; off; off >>= 1) {
    float os = __shfl_xor(bs, off, 64);
    int oi = __shfl_xor(bidx, off, 64);
    if (os > bs || (os == bs && oi < bidx)) { bs = os; bidx = oi; }
  }
  if (lane == 0) {
    float4 d = deltas[wid];
    float4 a = anchors[n];
    float aw = a.z - a.x, ah = a.w - a.y;
    float acx = a.x + 0.5f * aw, acy = a.y + 0.5f * ah;
    float dw = fminf(d.z, 4.0f), dh = fminf(d.w, 4.0f);
    float pcx = d.x * aw + acx;
    float pcy = d.y * ah + acy;
    float pw = expf(dw) * aw;
    float ph = expf(dh) * ah;
    float4 bx;
    bx.x = clip01(pcx - 0.5f * pw);
    bx.y = clip01(pcy - 0.5f * ph);
    bx.z = clip01(pcx + 0.5f * pw);
    bx.w = clip01(pcy + 0.5f * ph);
    boxes_out[wid] = bx;
    scores_out[wid] = bs;
    labels_out[wid] = (float)bidx;
    float bw = bx.z - bx.x, bh = bx.w - bx.y;
    bool valid = (bs > 0.5f) && (bw > 0.01f) && (bh > 0.01f) &&
                 (bw < 0.99f) && (bh < 0.99f);
    vbyte[wid] = valid ? 1 : 0;
    keys[wid] = ((u64)__float_as_uint(bs) << 32) | (unsigned int)(NN - 1 - n);
  }
}

// Rank pass 1: partial counts over a column SEGMENT. Also zero-inits dnm
// and (if provided) rowdeg/ovf for the sparse path.
__global__ __launch_bounds__(1024) void rank_part_kernel(
    const u64* __restrict__ keys, int* __restrict__ part,
    u64* __restrict__ dnm, unsigned int* rowdeg, unsigned int* ovf) {
  int b = blockIdx.z, seg = blockIdx.y, rb = blockIdx.x;
  int gid = ((blockIdx.z * NSEG + blockIdx.y) * gridDim.x + blockIdx.x) * 1024 +
            threadIdx.x;
  if (gid < DNM_WORDS) dnm[gid] = 0ull;
  if (rowdeg) {
    if (gid < NB * NN) rowdeg[gid] = 0u;
    if (gid < NB) ovf[gid] = 0u;
  }
  int r = threadIdx.x & 255;   // row slot
  int q = threadIdx.x >> 8;    // column quarter 0..3 (wave-uniform)
  int i = rb * 256 + r;
  const u64* kb = keys + (size_t)b * NN;
  u64 myk = kb[i];
  int cnt2 = 0;
  int j0 = seg * (NN / NSEG) + q * (NN / NSEG / 4);
  int j1 = j0 + NN / NSEG / 4;  // 256 iterations
#pragma unroll 8
  for (int j = j0; j < j1; ++j) {
    u64 kj = kb[j];  // wave-uniform address -> scalar load
    cnt2 += (kj > myk) ? 1 : 0;
  }
  __shared__ unsigned short partl[4][256];
  partl[q][r] = (unsigned short)cnt2;
  __syncthreads();
  if (threadIdx.x < 256) {
    int s = partl[0][r] + partl[1][r] + partl[2][r] + partl[3][r];
    part[((size_t)b * NSEG + seg) * NN + i] = s;
  }
}

// Rank pass 2: rank = sum of segment partials; scatter order/sbox/vbits.
__global__ __launch_bounds__(256) void rank_final_kernel(
    const int* __restrict__ part, const float4* __restrict__ boxes,
    const unsigned char* __restrict__ vbyte, int* __restrict__ order,
    float4* __restrict__ sbox, u64* __restrict__ vbits) {
  int b = blockIdx.y;
  int i = blockIdx.x * 256 + threadIdx.x;
  const int* pb = part + (size_t)b * NSEG * NN + i;
  int rank = 0;
#pragma unroll
  for (int s = 0; s < NSEG; ++s) rank += pb[(size_t)s * NN];
  order[(size_t)b * NN + rank] = i;
  sbox[(size_t)b * NN + rank] = boxes[(size_t)b * NN + i];
  if (vbyte[(size_t)b * NN + i])
    atomicOr(&vbits[b * 128 + (rank >> 6)], 1ull << (rank & 63));
}

// Monolithic rank (fallback path only, when ws can't hold part[]).
__global__ __launch_bounds__(1024) void rank_kernel(
    const u64* __restrict__ keys, const float4* __restrict__ boxes,
    const unsigned char* __restrict__ vbyte, int* __restrict__ order,
    float4* __restrict__ sbox, u64* __restrict__ vbits,
    u64* __restrict__ dnm) {
  int b = blockIdx.y;
  int gid = (blockIdx.y * gridDim.x + blockIdx.x) * 1024 + threadIdx.x;
  for (int z = gid; z < DNM_WORDS; z += 65536) dnm[z] = 0ull;
  int r = threadIdx.x & 255;
  int q = threadIdx.x >> 8;
  int i = blockIdx.x * 256 + r;
  const u64* kb = keys + (size_t)b * NN;
  u64 myk = kb[i];
  int cnt = 0;
  int j0 = q * (NN / 4), j1 = j0 + NN / 4;
#pragma unroll 8
  for (int j = j0; j < j1; ++j) {
    u64 kj = kb[j];
    cnt += (kj > myk) ? 1 : 0;
  }
  __shared__ unsigned short part[4][256];
  part[q][r] = (unsigned short)cnt;
  __syncthreads();
  if (threadIdx.x < 256) {
    int rank = part[0][r] + part[1][r] + part[2][r] + part[3][r];
    order[(size_t)b * NN + rank] = i;
    sbox[(size_t)b * NN + rank] = boxes[(size_t)b * NN + i];
    if (vbyte[(size_t)b * NN + i])
      atomicOr(&vbits[b * 128 + (rank >> 6)], 1ull << (rank & 63));
  }
}

// 64x64 tile of the (sorted-order) suppression matrix. Triangular grid.
// Diagonal tiles: upper half (self cleared) to mask[], lower half to dnm
// slot 0 (fixpoint masks). Off-diag bx>by: full word to mask[]; dq<4 also
// to dnm. Sparse path: each tile appends its upper-triangle column indices
// (j>i) to the row's fixed 64-entry list via one global atomicAdd
// reservation; overflow (deg>64) sets ovf[b] -> dense fallback. Entry order
// within a row is arbitrary (deposits are ORs).
__global__ __launch_bounds__(64) void build_kernel(
    const float4* __restrict__ sbox, u64* __restrict__ mask,
    u64* __restrict__ dnm, unsigned int* rowdeg,
    unsigned short* rowent, unsigned int* ovf) {
  int byq = blockIdx.y, bxq = blockIdx.x, b = blockIdx.z;
  int by, bx;
  if (bxq >= byq) {
    by = byq; bx = bxq;
  } else if (byq == 64) {
    return;
  } else {
    by = 128 - byq; bx = 127 - bxq;
  }
  int lane = threadIdx.x;
  __shared__ float4 cb[64];
  cb[lane] = sbox[(size_t)b * NN + bx * 64 + lane];
  __syncthreads();
  int i = by * 64 + lane;
  float4 rb = sbox[(size_t)b * NN + i];
  u64 word = 0;
  for (int jj = 0; jj < 64; ++jj)
    if (iou_pair(rb, cb[jj]) > 0.5f) word |= 1ull << jj;
  u64 ent;
  if (bx == by) {
    word &= ~(1ull << lane);  // clear self-IoU bit
    u64 lmask = (1ull << lane) - 1ull;
    mask[((size_t)b * ROWS + i) * 128 + bx] = word & ~lmask;
    dnm[(((size_t)b * 128 + by) * 4 + 0) * 64 + lane] = word & lmask;
    ent = word & ~lmask;  // j > i only
  } else {
    mask[((size_t)b * ROWS + i) * 128 + bx] = word;
    int dq = bx - by;
    if (dq < 4) dnm[(((size_t)b * 128 + by) * 4 + dq) * 64 + lane] = word;
    ent = word;  // whole tile is j > i
  }
  if (rowdeg && ent) {
    int wcnt = __popcll(ent);
    unsigned base = atomicAdd(&rowdeg[(size_t)b * NN + i], (unsigned)wcnt);
    if (base + (unsigned)wcnt <= (unsigned)ROW_CAP) {
      unsigned short* dst = rowent + ((size_t)b * NN + i) * ROW_CAP + base;
      int k = 0;
      u64 t = ent;
      while (t) {
        int bit = __builtin_ctzll(t);
        dst[k++] = (unsigned short)(bx * 64 + bit);
        t &= t - 1;
      }
    } else {
      atomicOr(&ovf[b], 1u);
    }
  }
}

// Sparse greedy reduce v16: TWO waves per batch, lbar-pipelined.
//  - Wave 1 = pure PREFETCHER: plain-C++ loads of chunk c+5's {diag, deg,
//    first-16 entries} (~30 VGPRs of rotating state -> the compiler KEEPS it
//    and inserts correct counted vmcnt waits, unlike the 76+-VGPR windows of
//    v10/v12/v15 which the allocator collapsed), then ds_writes chunk c+3
//    into a 4-slot LDS ring. lbar (lgkm-only) keeps its global loads in
//    flight across the barrier.
//  - Wave 0 = CONSUMER: zero global loads on its critical path. Per chunk:
//    LDS reads (stride-8B entry arrays: 2-way = conflict-free), ballot
//    fixpoint on the lower-triangle diag mask, kept lanes deposit entries
//    via LDS atomicOr up to the WAVE-MAX degree (shuffle-reduce; typ. 6-10
//    iters, not v15's fixed 32). deg>16 -> rare global slow path.
// Slot schedule: wave0 reads slot c&3 at body c; wave1 writes slot (c+3)&3
// (disjoint); a slot written at body c is read at body c+3 (lbar-visible)
// and overwritten at body c+4. Wave1's regs: set_{c&1} holds chunk c+3,
// issued at body c-2 (2-body latency slack).
__global__ __launch_bounds__(128) void reduce_sparse(
    const u64* __restrict__ vbits, const u64* __restrict__ dnm,
    const unsigned int* __restrict__ rowdeg,
    const unsigned short* __restrict__ rowent,
    const unsigned int* __restrict__ ovf, u64* __restrict__ keepw) {
  int b = blockIdx.x, tid = threadIdx.x;
  if (ovf[b]) return;  // dense fallback handles this batch (block-uniform)
  int lane = tid & 63, wave = tid >> 6;
  __shared__ u64 s_remv[128];
  __shared__ u64 s_keep[128];
  __shared__ u64 s_diag[4][64];
  __shared__ unsigned s_deg[4][64];
  __shared__ u64 s_e0[4][64], s_e1[4][64], s_e2[4][64], s_e3[4][64];

  const u64* dnb = dnm + (size_t)b * 128 * 4 * 64;
  const unsigned* dgb = rowdeg + (size_t)b * NN;
  const unsigned short* reb = rowent + (size_t)b * NN * ROW_CAP;

  u64 va = 0, vb2 = 0;
  u64 dA = 0, dB = 0;
  unsigned gA = 0, gB = 0;
  u64x2 eA0{}, eA1{}, eB0{}, eB1{};
  if (wave == 0) {
    s_remv[2 * lane] = 0ull;
    s_remv[2 * lane + 1] = 0ull;
    va = vbits[b * 128 + 2 * lane];
    vb2 = vbits[b * 128 + 2 * lane + 1];
  } else {
    // Prologue: chunks 0..2 -> slots 0..2; issue chunks 3,4 into sets A,B.
    for (int cc = 0; cc < 3; ++cc) {
      int row = cc * 64 + lane;
      u64 d = dnb[(size_t)cc * 256 + lane];
      unsigned g = dgb[row];
      const u64x2* p = (const u64x2*)(reb + (size_t)row * ROW_CAP);
      u64x2 e0 = p[0], e1 = p[1];
      s_diag[cc][lane] = d;
      s_deg[cc][lane] = g;
      s_e0[cc][lane] = e0[0];
      s_e1[cc][lane] = e0[1];
      s_e2[cc][lane] = e1[0];
      s_e3[cc][lane] = e1[1];
    }
    {
      int row = 3 * 64 + lane;
      dA = dnb[(size_t)3 * 256 + lane];
      gA = dgb[row];
      const u64x2* p = (const u64x2*)(reb + (size_t)row * ROW_CAP);
      eA0 = p[0];
      eA1 = p[1];
    }
    {
      int row = 4 * 64 + lane;
      dB = dnb[(size_t)4 * 256 + lane];
      gB = dgb[row];
      const u64x2* p = (const u64x2*)(reb + (size_t)row * ROW_CAP);
      eB0 = p[0];
      eB1 = p[1];
    }
  }
  lbar();  // slots 0..2 + s_remv visible; A/B loads stay in flight

  for (int c = 0; c < 128; ++c) {
    if (wave == 1) {
      // Write chunk c+3 from set_{c&1} (issued at body c-2), reissue c+5.
      if (c + 3 < 128) {
        int slot = (c + 3) & 3;
        if (c & 1) {
          s_diag[slot][lane] = dB;
          s_deg[slot][lane] = gB;
          s_e0[slot][lane] = eB0[0];
          s_e1[slot][lane] = eB0[1];
          s_e2[slot][lane] = eB1[0];
          s_e3[slot][lane] = eB1[1];
        } else {
          s_diag[slot][lane] = dA;
          s_deg[slot][lane] = gA;
          s_e0[slot][lane] = eA0[0];
          s_e1[slot][lane] = eA0[1];
          s_e2[slot][lane] = eA1[0];
          s_e3[slot][lane] = eA1[1];
        }
      }
      int cp = (c + 5 < 128) ? c + 5 : 127;
      int row = cp * 64 + lane;
      const u64x2* p = (const u64x2*)(reb + (size_t)row * ROW_CAP);
      if (c & 1) {
        dB = dnb[(size_t)cp * 256 + lane];
        gB = dgb[row];
        eB0 = p[0];
        eB1 = p[1];
      } else {
        dA = dnb[(size_t)cp * 256 + lane];
        gA = dgb[row];
        eA0 = p[0];
        eA1 = p[1];
      }
    } else {
      int slot = c & 3;
      u64 dcur = s_diag[slot][lane];
      unsigned deg = s_deg[slot][lane];
      u64 q0 = s_e0[slot][lane], q1 = s_e1[slot][lane];
      u64 q2 = s_e2[slot][lane], q3 = s_e3[slot][lane];
      u64 rm = s_remv[c];
      u64 vbw = readlane64((c & 1) ? vb2 : va, c >> 1);
      u64 cand = readfirstlane64(vbw & ~rm);
      // Ballot fixpoint: dcur = lane's lower-triangle column mask.
      u64 kept = cand;
      while (true) {
        u64 sup = __ballot((dcur & kept) != 0ull);
        u64 nk = cand & ~sup;
        if (nk == kept) break;
        kept = nk;
      }
      bool isk = (kept >> lane) & 1;
      int lim = (isk && deg) ? ((int)deg < 16 ? (int)deg : 16) : 0;
      int wmax = lim;  // wave-max degree -> uniform short loop
      for (int off = 32; off; off >>= 1) {
        int t = __shfl_xor(wmax, off, 64);
        wmax = t > wmax ? t : wmax;
      }
      for (int k = 0; k < wmax; ++k) {
        if (k < lim) {
          u64 src = (k < 8) ? (k < 4 ? q0 : q1) : (k < 12 ? q2 : q3);
          int j = (int)((src >> ((k & 3) * 16)) & 0xFFFFull);
          atomicOr(&s_remv[j >> 6], 1ull << (j & 63));
        }
      }
      if (__ballot(isk && (int)deg > 16)) {  // rare long rows
        if (isk && (int)deg > 16) {
          const unsigned short* rp = reb + (size_t)(c * 64 + lane) * ROW_CAP;
          for (int k = 16; k < (int)deg; ++k) {
            int j = rp[k];
            atomicOr(&s_remv[j >> 6], 1ull << (j & 63));
          }
        }
      }
      if (lane == 0) s_keep[c] = kept;
    }
    lbar();
  }

  if (wave == 0) {
    keepw[b * 128 + 2 * lane] = s_keep[2 * lane];
    keepw[b * 128 + 2 * lane + 1] = s_keep[2 * lane + 1];
  }
}

struct TSet {
  u64x2 t0, t1, t2, t3, t4, t5, t6, t7, t8, t9;
};

// Dense greedy reduce (v13 machinery) — overflow/small-ws fallback.
// If ovf != nullptr it runs ONLY when ovf[b] is set.
__global__ __launch_bounds__(512) void reduce_dense(
    u64* __restrict__ mask, const u64* __restrict__ vbits,
    const u64* __restrict__ dnm, const unsigned int* __restrict__ ovf,
    u64* __restrict__ keepw) {
  int b = blockIdx.x, tid = threadIdx.x;
  if (ovf && ovf[b] == 0) return;
  int lane = tid & 63, wave = tid >> 6;
  __shared__ u64 s_remv[128];
  __shared__ u64 s_keep[128];
  __shared__ int s_rowlist[2][80];
  u64* mbz = mask + (size_t)b * ROWS * 128;
  const u64* mb = mbz;
  const u64* dn = dnm + (size_t)b * 128 * 4 * 64;

  for (int w = tid; w < 128; w += 512) {
    s_remv[w] = 0ull;
    mbz[(size_t)NN * 128 + w] = 0ull;  // zero row (dead-load target)
  }
  if (tid < 160) s_rowlist[tid / 80][tid % 80] = NN;

  u64 va = 0, vb2 = 0;
  u64 dA = 0, nA = 0, mA = 0, oA = 0, dB = 0, nB = 0, mB = 0, oB = 0;
  u64 dC = 0, nC = 0, mC = 0, oC = 0, dD = 0, nD = 0, mD = 0, oD = 0;
  if (wave == 0) {
    va = vbits[b * 128 + 2 * lane];
    vb2 = vbits[b * 128 + 2 * lane + 1];
    const u64* r0 = dn + lane;
    dA = r0[0]; nA = r0[64]; mA = r0[128]; oA = r0[192];
    const u64* r1 = dn + 4 * 64 + lane;
    dB = r1[0]; nB = r1[64]; mB = r1[128]; oB = r1[192];
  }
  TSet U{}, V{};
  int w0i = 2 * lane;
  __syncthreads();

  auto serial_body = [&](int c, u64 dcur, u64 ncur, u64 mcur, u64 ocur,
                         u64& dnew, u64& nnew, u64& mnew, u64& onew) {
    int cp = (c + 2 < 128) ? (c + 2) : 127;
    const u64* rp = dn + (size_t)cp * 4 * 64 + lane;
    dnew = rp[0]; nnew = rp[64]; mnew = rp[128]; onew = rp[192];
    int par = c & 1;
    u64 rm = s_remv[c];
    u64 vbw = readlane64(par ? vb2 : va, c >> 1);
    u64 cand = readfirstlane64(vbw & ~rm);
    u64 kept = cand;
    while (true) {
      u64 sup = __ballot((dcur & kept) != 0ull);
      u64 nk = cand & ~sup;
      if (nk == kept) break;
      kept = nk;
    }
    bool isk = (kept >> lane) & 1;
    if (c + 1 < 128 && isk && ncur) atomicOr(&s_remv[c + 1], ncur);
    if (c + 2 < 128 && isk && mcur) atomicOr(&s_remv[c + 2], mcur);
    if (c + 3 < 128 && isk && ocur) atomicOr(&s_remv[c + 3], ocur);
    s_rowlist[par][lane] = NN;
    if (isk) {
      int pos = __popcll(kept & ((1ull << lane) - 1ull));
      s_rowlist[par][pos] = c * 64 + lane;
    }
    if (lane == 0) s_keep[c] = kept;
  };

  auto bg_body = [&](int c, TSet& T) {
    u64 ax = T.t0[0] | T.t1[0] | T.t2[0] | T.t3[0] | T.t4[0] | T.t5[0] |
             T.t6[0] | T.t7[0] | T.t8[0] | T.t9[0];
    u64 ay = T.t0[1] | T.t1[1] | T.t2[1] | T.t3[1] | T.t4[1] | T.t5[1] |
             T.t6[1] | T.t7[1] | T.t8[1] | T.t9[1];
    int sc = (c + 1) & ~1;
    int wx = sc + w0i, wy = wx + 1;
    if (wx > c && wx < 128 && ax) atomicOr(&s_remv[wx], ax);
    if (wy > c && wy < 128 && ay) atomicOr(&s_remv[wy], ay);
    const int* rl = s_rowlist[(c - 1) & 1];
    int base = wave - 1;
    int si = (c + 3) & ~1;
    int w = si + w0i;
    bool wok = w < 128;
    const u64* mw = mb + w;
    const u64* zp = mbz + (size_t)NN * 128;
    int r0 = rl[base], r1 = rl[base + 7], r2 = rl[base + 14],
        r3 = rl[base + 21], r4 = rl[base + 28], r5 = rl[base + 35],
        r6 = rl[base + 42], r7 = rl[base + 49], r8 = rl[base + 56],
        r9 = rl[base + 63];
    T.t0 = *(const u64x2*)((wok && r0 != NN) ? mw + (size_t)r0 * 128 : zp);
    T.t1 = *(const u64x2*)((wok && r1 != NN) ? mw + (size_t)r1 * 128 : zp);
    T.t2 = *(const u64x2*)((wok && r2 != NN) ? mw + (size_t)r2 * 128 : zp);
    T.t3 = *(const u64x2*)((wok && r3 != NN) ? mw + (size_t)r3 * 128 : zp);
    T.t4 = *(const u64x2*)((wok && r4 != NN) ? mw + (size_t)r4 * 128 : zp);
    T.t5 = *(const u64x2*)((wok && r5 != NN) ? mw + (size_t)r5 * 128 : zp);
    T.t6 = *(const u64x2*)((wok && r6 != NN) ? mw + (size_t)r6 * 128 : zp);
    T.t7 = *(const u64x2*)((wok && r7 != NN) ? mw + (size_t)r7 * 128 : zp);
    T.t8 = *(const u64x2*)((wok && r8 != NN) ? mw + (size_t)r8 * 128 : zp);
    T.t9 = *(const u64x2*)((wok && r9 != NN) ? mw + (size_t)r9 * 128 : zp);
  };

  for (int c = 0; c < 128; c += 4) {
    if (wave == 0) serial_body(c, dA, nA, mA, oA, dC, nC, mC, oC);
    else bg_body(c, U);
    lbar();
    if (wave == 0) serial_body(c + 1, dB, nB, mB, oB, dD, nD, mD, oD);
    else bg_body(c + 1, V);
    lbar();
    if (wave == 0) serial_body(c + 2, dC, nC, mC, oC, dA, nA, mA, oA);
    else bg_body(c + 2, U);
    lbar();
    if (wave == 0) serial_body(c + 3, dD, nD, mD, oD, dB, nB, mB, oB);
    else bg_body(c + 3, V);
    lbar();
  }

  __syncthreads();
  for (int w = tid; w < 128; w += 512) keepw[b * 128 + w] = s_keep[w];
}

// Scatter keep bits back to original anchor order (parallel epilogue).
__global__ __launch_bounds__(256) void scatter_keep(
    const u64* __restrict__ keepw, const int* __restrict__ order,
    float* __restrict__ keep_out) {
  int b = blockIdx.y;
  int p = blockIdx.x * 256 + threadIdx.x;
  int orig = order[(size_t)b * NN + p];
  keep_out[(size_t)b * NN + orig] =
      ((keepw[b * 128 + (p >> 6)] >> (p & 63)) & 1) ? 1.0f : 0.0f;
}

// Slow-but-correct fallback if d_ws can't hold the mask.
__global__ __launch_bounds__(1024) void nms_fallback(
    const float4* __restrict__ sbox, const u64* __restrict__ vbits,
    const int* __restrict__ order, float* __restrict__ keep_out) {
  int b = blockIdx.x, tid = threadIdx.x;
  __shared__ u64 dead[128];
  __shared__ int s_next;
  __shared__ float4 s_box;
  for (int w = tid; w < 128; w += 1024) dead[w] = ~vbits[b * 128 + w];
  for (int p = tid; p < NN; p += 1024)
    keep_out[(size_t)b * NN + order[(size_t)b * NN + p]] = 0.0f;
  __syncthreads();
  int i = 0;
  while (true) {
    if (tid == 0) {
      int nxt = NN;
      int w = i >> 6;
      u64 live = ~dead[w] & (~0ull << (i & 63));
      while (true) {
        if (live) { nxt = w * 64 + __builtin_ctzll(live); break; }
        if (++w >= 128) break;
        live = ~dead[w];
      }
      s_next = nxt;
      if (nxt < NN) {
        s_box = sbox[(size_t)b * NN + nxt];
        keep_out[(size_t)b * NN + order[(size_t)b * NN + nxt]] = 1.0f;
      }
    }
    __syncthreads();
    i = s_next;
    if (i >= NN) break;
    float4 kb = s_box;
    for (int j = i + 1 + tid; j < NN; j += 1024) {
      if (iou_pair(kb, sbox[(size_t)b * NN + j]) > 0.5f)
        atomicOr(&dead[j >> 6], 1ull << (j & 63));
    }
    __syncthreads();
    i = i + 1;
  }
}

extern "C" void kernel_launch(void* const* d_in, const int* in_sizes, int n_in,
                              void* d_out, int out_size, void* d_ws, size_t ws_size,
                              hipStream_t stream) {
  const float* logits = (const float*)d_in[0];
  const float4* deltas = (const float4*)d_in[1];
  const float4* anchors = (const float4*)d_in[2];
  float* out = (float*)d_out;
  float4* boxes_out = (float4*)(out + OFF_BOXES);
  float* scores_out = out + OFF_SCORES;
  float* labels_out = out + OFF_LABELS;
  float* keep_out = out + OFF_KEEP;
  float* all_out = out + OFF_ALL;

  char* ws = (char*)d_ws;
  u64* keys = (u64*)(ws + WS_KEYS);
  unsigned char* vbyte = (unsigned char*)(ws + WS_VBYTE);
  int* order = (int*)(ws + WS_ORDER);
  float4* sbox = (float4*)(ws + WS_SBOX);
  u64* vbits = (u64*)(ws + WS_VBITS);
  u64* mask = (u64*)(ws + WS_MASK);
  u64* dnm = (u64*)(ws + WS_DNM);
  int* part = (int*)(ws + WS_PART);
  unsigned int* rowdeg = (unsigned int*)(ws + WS_RDEG);
  unsigned short* rowent = (unsigned short*)(ws + WS_RENT);
  unsigned int* ovf = (unsigned int*)(ws + WS_OVF);
  u64* keepw = (u64*)(ws + WS_KEYS);  // reuses keys region (dead post-rank)

  decode_kernel<<<dim3(NB * NN / 4), dim3(256), 0, stream>>>(
      logits, deltas, anchors, boxes_out, scores_out, labels_out, all_out,
      keys, vbyte, vbits);
  if (ws_size >= WS_TOTAL_SPARSE) {
    rank_part_kernel<<<dim3(NN / 256, NSEG, NB), dim3(1024), 0, stream>>>(
        keys, part, dnm, rowdeg, ovf);
    rank_final_kernel<<<dim3(NN / 256, NB), dim3(256), 0, stream>>>(
        part, (const float4*)boxes_out, vbyte, order, sbox, vbits);
    build_kernel<<<dim3(128, 65, NB), dim3(64), 0, stream>>>(
        sbox, mask, dnm, rowdeg, rowent, ovf);
    reduce_sparse<<<dim3(NB), dim3(128), 0, stream>>>(vbits, dnm, rowdeg,
                                                      rowent, ovf, keepw);
    reduce_dense<<<dim3(NB), dim3(512), 0, stream>>>(mask, vbits, dnm, ovf,
                                                     keepw);
    scatter_keep<<<dim3(NN / 256, NB), dim3(256), 0, stream>>>(keepw, order,
                                                               keep_out);
  } else if (ws_size >= WS_TOTAL) {
    rank_part_kernel<<<dim3(NN / 256, NSEG, NB), dim3(1024), 0, stream>>>(
        keys, part, dnm, nullptr, nullptr);
    rank_final_kernel<<<dim3(NN / 256, NB), dim3(256), 0, stream>>>(
        part, (const float4*)boxes_out, vbyte, order, sbox, vbits);
    build_kernel<<<dim3(128, 65, NB), dim3(64), 0, stream>>>(
        sbox, mask, dnm, nullptr, nullptr, nullptr);
    reduce_dense<<<dim3(NB), dim3(512), 0, stream>>>(mask, vbits, dnm, nullptr,
                                                     keepw);
    scatter_keep<<<dim3(NN / 256, NB), dim3(256), 0, stream>>>(keepw, order,
                                                               keep_out);
  } else if (ws_size >= WS_TOTAL_OLD) {
    rank_kernel<<<dim3(NN / 256, NB), dim3(1024), 0, stream>>>(
        keys, (const float4*)boxes_out, vbyte, order, sbox, vbits, dnm);
    build_kernel<<<dim3(128, 65, NB), dim3(64), 0, stream>>>(
        sbox, mask, dnm, nullptr, nullptr, nullptr);
    reduce_dense<<<dim3(NB), dim3(512), 0, stream>>>(mask, vbits, dnm, nullptr,
                                                     keepw);
    scatter_keep<<<dim3(NN / 256, NB), dim3(256), 0, stream>>>(keepw, order,
                                                               keep_out);
  } else {
    rank_kernel<<<dim3(NN / 256, NB), dim3(1024), 0, stream>>>(
        keys, (const float4*)boxes_out, vbyte, order, sbox, vbits, dnm);
    nms_fallback<<<dim3(NB), dim3(1024), 0, stream>>>(sbox, vbits, order,
                                                      keep_out);
  }
}

// Round 12
// 251.550 us; speedup vs baseline: 1.1413x; 1.1413x over previous
//
#include <hip/hip_runtime.h>

// Problem constants (fixed by reference): B=2, N=8192, C=80
constexpr int NB = 2;
constexpr int NN = 8192;
constexpr int NC = 80;
constexpr int ROWS = NN + 1;  // mask rows per batch; row NN is an all-zero row

// d_out layout (floats), in reference return order:
// boxes[B,N,4], max_scores[B,N], labels[B,N], keep[B,N], all_scores[B,N,C]
constexpr size_t OFF_BOXES  = 0;
constexpr size_t OFF_SCORES = (size_t)NB * NN * 4;
constexpr size_t OFF_LABELS = OFF_SCORES + (size_t)NB * NN;
constexpr size_t OFF_KEEP   = OFF_LABELS + (size_t)NB * NN;
constexpr size_t OFF_ALL    = OFF_KEEP + (size_t)NB * NN;

// d_ws layout
constexpr size_t WS_KEYS  = 0;                                   // B*N u64
constexpr size_t WS_VBYTE = WS_KEYS + (size_t)NB * NN * 8;       // B*N u8
constexpr size_t WS_ORDER = WS_VBYTE + (size_t)NB * NN;          // B*N i32
constexpr size_t WS_SBOX  = WS_ORDER + (size_t)NB * NN * 4;      // B*N float4
constexpr size_t WS_VBITS = WS_SBOX + (size_t)NB * NN * 16;      // B*128 u64
constexpr size_t WS_MASK  = WS_VBITS + (size_t)NB * 128 * 8;     // B*ROWS*128 u64
constexpr size_t WS_DNM   = WS_MASK + (size_t)NB * ROWS * 128 * 8; // B*128*4*64 u64
constexpr size_t WS_PART  = WS_DNM + (size_t)NB * 128 * 4 * 64 * 8; // B*8*N i32
constexpr size_t WS_TOTAL = WS_PART + (size_t)NB * 8 * NN * 4;
constexpr size_t WS_TOTAL_OLD = WS_PART;
// Chunk-128 extension: dnm2[row][6] = {dw0, dw1, n0, n1, m0, m1}
//  dw0/dw1: in-chunk lower-triangle mask (128-bit, pre-masked to cols < row)
//  n0/n1:   row's suppression words of the NEXT 128-chunk
//  m0/m1:   row's suppression words of the chunk after that
constexpr size_t WS_DNM2 = WS_TOTAL;                              // B*N*6 u64
constexpr size_t WS_TOTAL_128 = WS_DNM2 + (size_t)NB * NN * 6 * 8;
constexpr int DNM_WORDS = NB * 128 * 4 * 64;   // 65536 (old path)
constexpr int DNM2_WORDS = NB * NN * 6;        // 98304
constexpr int NSEG = 8;                        // rank column segments

typedef unsigned long long u64;
typedef __attribute__((ext_vector_type(2))) unsigned long long u64x2;

// lgkmcnt(0)-only barrier: keeps global loads in flight across it.
__device__ inline void lbar() {
  __builtin_amdgcn_s_waitcnt(0xc07f);
  __builtin_amdgcn_s_barrier();
}

__device__ inline u64 readlane64(u64 v, int src) {
  unsigned int lo = (unsigned int)__builtin_amdgcn_readlane((int)(unsigned int)v, src);
  unsigned int hi = (unsigned int)__builtin_amdgcn_readlane((int)(unsigned int)(v >> 32), src);
  return ((u64)hi << 32) | lo;
}

__device__ inline u64 readfirstlane64(u64 v) {
  unsigned int lo = (unsigned int)__builtin_amdgcn_readfirstlane((int)(unsigned int)v);
  unsigned int hi = (unsigned int)__builtin_amdgcn_readfirstlane((int)(unsigned int)(v >> 32));
  return ((u64)hi << 32) | lo;
}

// IoU exactly mirroring the numpy op order; contraction off so f32 rounding
// matches numpy bit-for-bit. Bit-exactly SYMMETRIC in (p,q).
__device__ inline float iou_pair(const float4 p, const float4 q) {
#pragma clang fp contract(off)
  float areaA = (p.z - p.x) * (p.w - p.y);
  float areaB = (q.z - q.x) * (q.w - q.y);
  float ix1 = fmaxf(p.x, q.x);
  float iy1 = fmaxf(p.y, q.y);
  float ix2 = fminf(p.z, q.z);
  float iy2 = fminf(p.w, q.w);
  float inter = fmaxf(ix2 - ix1, 0.0f) * fmaxf(iy2 - iy1, 0.0f);
  float uni = areaA + areaB - inter;
  return inter / fmaxf(uni, 1e-9f);
}

__device__ inline float clip01(float v) { return fminf(fmaxf(v, 0.0f), 1.0f); }

// One wave per (b,n): sigmoid all 80 classes, max/argmax (first-index ties),
// box decode, validity, sort key. Also zero-inits vbits.
__global__ __launch_bounds__(256) void decode_kernel(
    const float* __restrict__ logits, const float4* __restrict__ deltas,
    const float4* __restrict__ anchors, float4* __restrict__ boxes_out,
    float* __restrict__ scores_out, float* __restrict__ labels_out,
    float* __restrict__ all_out, u64* __restrict__ keys,
    unsigned char* __restrict__ vbyte, u64* __restrict__ vbits) {
#pragma clang fp contract(off)
  if (blockIdx.x == 0 && threadIdx.x < NB * 128) vbits[threadIdx.x] = 0ull;
  int wid = (blockIdx.x * 256 + threadIdx.x) >> 6;  // 0 .. B*N-1
  int lane = threadIdx.x & 63;
  int n = wid & (NN - 1);
  size_t base = (size_t)wid * NC;

  float x0 = logits[base + lane];
  float sig0 = 1.0f / (1.0f + expf(-x0));
  all_out[base + lane] = sig0;
  float bs = sig0;
  int bidx = lane;
  if (lane < NC - 64) {
    float x1 = logits[base + 64 + lane];
    float sig1 = 1.0f / (1.0f + expf(-x1));
    all_out[base + 64 + lane] = sig1;
    if (sig1 > bs) { bs = sig1; bidx = lane + 64; }  // tie -> smaller idx wins
  }
  for (int off = 32; off; off >>= 1) {
    float os = __shfl_xor(bs, off, 64);
    int oi = __shfl_xor(bidx, off, 64);
    if (os > bs || (os == bs && oi < bidx)) { bs = os; bidx = oi; }
  }
  if (lane == 0) {
    float4 d = deltas[wid];
    float4 a = anchors[n];
    float aw = a.z - a.x, ah = a.w - a.y;
    float acx = a.x + 0.5f * aw, acy = a.y + 0.5f * ah;
    float dw = fminf(d.z, 4.0f), dh = fminf(d.w, 4.0f);
    float pcx = d.x * aw + acx;
    float pcy = d.y * ah + acy;
    float pw = expf(dw) * aw;
    float ph = expf(dh) * ah;
    float4 bx;
    bx.x = clip01(pcx - 0.5f * pw);
    bx.y = clip01(pcy - 0.5f * ph);
    bx.z = clip01(pcx + 0.5f * pw);
    bx.w = clip01(pcy + 0.5f * ph);
    boxes_out[wid] = bx;
    scores_out[wid] = bs;
    labels_out[wid] = (float)bidx;
    float bw = bx.z - bx.x, bh = bx.w - bx.y;
    bool valid = (bs > 0.5f) && (bw > 0.01f) && (bh > 0.01f) &&
                 (bw < 0.99f) && (bh < 0.99f);
    vbyte[wid] = valid ? 1 : 0;
    keys[wid] = ((u64)__float_as_uint(bs) << 32) | (unsigned int)(NN - 1 - n);
  }
}

// Rank pass 1: partial counts over a column SEGMENT. Zero-inits dnm2 (new
// path) or old dnm (fallback path).
__global__ __launch_bounds__(1024) void rank_part_kernel(
    const u64* __restrict__ keys, int* __restrict__ part,
    u64* __restrict__ dnm, u64* __restrict__ dnm2) {
  int b = blockIdx.z, seg = blockIdx.y, rb = blockIdx.x;
  int gid = ((blockIdx.z * NSEG + blockIdx.y) * gridDim.x + blockIdx.x) * 1024 +
            threadIdx.x;
  if (dnm2) {
    if (gid < DNM2_WORDS) dnm2[gid] = 0ull;
  } else {
    if (gid < DNM_WORDS) dnm[gid] = 0ull;
  }
  int r = threadIdx.x & 255;   // row slot
  int q = threadIdx.x >> 8;    // column quarter 0..3 (wave-uniform)
  int i = rb * 256 + r;
  const u64* kb = keys + (size_t)b * NN;
  u64 myk = kb[i];
  int cnt2 = 0;
  int j0 = seg * (NN / NSEG) + q * (NN / NSEG / 4);
  int j1 = j0 + NN / NSEG / 4;  // 256 iterations
#pragma unroll 8
  for (int j = j0; j < j1; ++j) {
    u64 kj = kb[j];  // wave-uniform address -> scalar load
    cnt2 += (kj > myk) ? 1 : 0;
  }
  __shared__ unsigned short partl[4][256];
  partl[q][r] = (unsigned short)cnt2;
  __syncthreads();
  if (threadIdx.x < 256) {
    int s = partl[0][r] + partl[1][r] + partl[2][r] + partl[3][r];
    part[((size_t)b * NSEG + seg) * NN + i] = s;
  }
}

// Rank pass 2: rank = sum of segment partials; scatter order/sbox/vbits.
__global__ __launch_bounds__(256) void rank_final_kernel(
    const int* __restrict__ part, const float4* __restrict__ boxes,
    const unsigned char* __restrict__ vbyte, int* __restrict__ order,
    float4* __restrict__ sbox, u64* __restrict__ vbits) {
  int b = blockIdx.y;
  int i = blockIdx.x * 256 + threadIdx.x;
  const int* pb = part + (size_t)b * NSEG * NN + i;
  int rank = 0;
#pragma unroll
  for (int s = 0; s < NSEG; ++s) rank += pb[(size_t)s * NN];
  order[(size_t)b * NN + rank] = i;
  sbox[(size_t)b * NN + rank] = boxes[(size_t)b * NN + i];
  if (vbyte[(size_t)b * NN + i])
    atomicOr(&vbits[b * 128 + (rank >> 6)], 1ull << (rank & 63));
}

// Monolithic rank (fallback path only, when ws can't hold part[]).
__global__ __launch_bounds__(1024) void rank_kernel(
    const u64* __restrict__ keys, const float4* __restrict__ boxes,
    const unsigned char* __restrict__ vbyte, int* __restrict__ order,
    float4* __restrict__ sbox, u64* __restrict__ vbits,
    u64* __restrict__ dnm) {
  int b = blockIdx.y;
  int gid = (blockIdx.y * gridDim.x + blockIdx.x) * 1024 + threadIdx.x;
  for (int z = gid; z < DNM_WORDS; z += 65536) dnm[z] = 0ull;
  int r = threadIdx.x & 255;
  int q = threadIdx.x >> 8;
  int i = blockIdx.x * 256 + r;
  const u64* kb = keys + (size_t)b * NN;
  u64 myk = kb[i];
  int cnt = 0;
  int j0 = q * (NN / 4), j1 = j0 + NN / 4;
#pragma unroll 8
  for (int j = j0; j < j1; ++j) {
    u64 kj = kb[j];
    cnt += (kj > myk) ? 1 : 0;
  }
  __shared__ unsigned short part[4][256];
  part[q][r] = (unsigned short)cnt;
  __syncthreads();
  if (threadIdx.x < 256) {
    int rank = part[0][r] + part[1][r] + part[2][r] + part[3][r];
    order[(size_t)b * NN + rank] = i;
    sbox[(size_t)b * NN + rank] = boxes[(size_t)b * NN + i];
    if (vbyte[(size_t)b * NN + i])
      atomicOr(&vbits[b * 128 + (rank >> 6)], 1ull << (rank & 63));
  }
}

// 64x64 tile of the (sorted-order) suppression matrix. Triangular grid.
// mask[]: full rows (bg consumption). dnm2 path (chunk-128 reduce):
//  - diagonal tile (bx==by): writes the row's in-chunk lower-triangle word
//    (dw0 for rows with in-chunk pos < 64, dw1 for pos >= 64).
//  - sub-diagonal-adjacent tile (bx==by+1, same chunk): ALSO computes the
//    TRANSPOSE via symmetric re-evaluation (iou is bit-exactly symmetric)
//    and writes dw0 for the bx-tile's rows (their cols 0..63, all < row).
//  - chunk-distance 1 tiles -> n0/n1; distance 2 -> m0/m1.
// dnm2==nullptr: legacy dnm writes (64-chunk dense fallback).
__global__ __launch_bounds__(64) void build_kernel(
    const float4* __restrict__ sbox, u64* __restrict__ mask,
    u64* __restrict__ dnm, u64* __restrict__ dnm2) {
  int byq = blockIdx.y, bxq = blockIdx.x, b = blockIdx.z;
  int by, bx;
  if (bxq >= byq) {
    by = byq; bx = bxq;
  } else if (byq == 64) {
    return;
  } else {
    by = 128 - byq; bx = 127 - bxq;
  }
  int lane = threadIdx.x;
  __shared__ float4 cb[64];
  __shared__ float4 rbs[64];
  cb[lane] = sbox[(size_t)b * NN + bx * 64 + lane];
  __syncthreads();
  int i = by * 64 + lane;
  float4 rb = sbox[(size_t)b * NN + i];
  u64 word = 0;
  for (int jj = 0; jj < 64; ++jj)
    if (iou_pair(rb, cb[jj]) > 0.5f) word |= 1ull << jj;
  if (bx == by) {
    word &= ~(1ull << lane);  // clear self-IoU bit
    u64 lmask = (1ull << lane) - 1ull;
    mask[((size_t)b * ROWS + i) * 128 + bx] = word & ~lmask;
    if (dnm2) {
      // in-chunk lower mask: slot 0 if pos<64 (tile even in chunk), else 1
      dnm2[((size_t)b * NN + i) * 6 + ((by & 1) ? 1 : 0)] = word & lmask;
    } else {
      dnm[(((size_t)b * 128 + by) * 4 + 0) * 64 + lane] = word & lmask;
    }
  } else {
    mask[((size_t)b * ROWS + i) * 128 + bx] = word;
    if (dnm2) {
      int dq = (bx >> 1) - (by >> 1);  // chunk distance
      if (dq == 0) {
        // bx == by+1 within the same chunk (by even-in-chunk). Transpose:
        // rows of tile bx need their cols over tile by as dw0.
        rbs[lane] = rb;
        __syncthreads();  // block-uniform branch (bx,by from blockIdx)
        float4 myc = cb[lane];  // box of row bx*64+lane
        u64 cm = 0;
        for (int jj = 0; jj < 64; ++jj)
          if (iou_pair(myc, rbs[jj]) > 0.5f) cm |= 1ull << jj;
        dnm2[((size_t)b * NN + bx * 64 + lane) * 6 + 0] = cm;
      } else if (dq == 1) {
        dnm2[((size_t)b * NN + i) * 6 + 2 + (bx & 1)] = word;
      } else if (dq == 2) {
        dnm2[((size_t)b * NN + i) * 6 + 4 + (bx & 1)] = word;
      }
    } else {
      int dq = bx - by;
      if (dq < 4) dnm[(((size_t)b * 128 + by) * 4 + dq) * 64 + lane] = word;
    }
  }
}

// Greedy reduce v17 — CHUNK = 128 boxes, 64 serial bodies (half of the
// 128-body structures that all plateaued at ~1700-2400 cy/body regardless
// of data movement: the cost is per-BODY fixed, so fewer bodies wins).
// Block = 1024 threads = 16 waves.
//  - Wave 0: per body, 128-bit ballot fixpoint. Lane owns rows c*128+lane
//    (lo) and +64+lane (hi). Masks from dnm2 (pre-masked lower-triangle).
//    Kept rows deposit their next-TWO-chunk words (n,m from dnm2) into
//    s_remv; 2-slot (even/odd body) register prefetch, 2-body slack.
//  - Waves 1..15: single-buffered 9-row mask loads (36 VGPR/set, held
//    across ONE lbar -- sized to survive register allocation, unlike the
//    80-VGPR double buffers of v10/v12 which collapsed). At body c: consume
//    rows kept at chunk c-2 (loaded at body c-1, start word 2c+2 ==
//    exactly the uncovered words), then issue rows kept at chunk c-1
//    (start word 2c+4, consumed at body c+1). Pad slots hit the zero row.
// Coverage: chunk k (words 2k,2k+1) gets in-chunk (fixpoint), k-1 (wave0 n
// at body k-1), k-2 (wave0 m at body k-2), <= k-3 (bg loads start word
// 2j+6 <= 2k, deposited at body j+2 <= k-1, lbar-visible). Complete.
__global__ __launch_bounds__(1024) void reduce128(
    u64* __restrict__ mask, const u64* __restrict__ vbits,
    const u64* __restrict__ dnm2, u64* __restrict__ keepw) {
  int b = blockIdx.x, tid = threadIdx.x;
  int lane = tid & 63, wave = tid >> 6;
  __shared__ u64 s_remv[128];
  __shared__ u64 s_keep[128];
  __shared__ int s_rowlist[2][144];
  u64* mbz = mask + (size_t)b * ROWS * 128;
  const u64* mb = mbz;
  const u64* d2 = dnm2 + (size_t)b * NN * 6;

  for (int w = tid; w < 128; w += 1024) {
    s_remv[w] = 0ull;
    mbz[(size_t)NN * 128 + w] = 0ull;  // zero row (pad-slot load target)
  }
  for (int w = tid; w < 288; w += 1024) s_rowlist[w / 144][w % 144] = NN;

  // Wave 0 state: vbits + two body slots (A even, B odd), 11 u64 each.
  u64 va = 0, vb2 = 0;
  u64 Adl0 = 0, Aln0 = 0, Aln1 = 0, Alm0 = 0, Alm1 = 0;
  u64 Adh0 = 0, Adh1 = 0, Ahn0 = 0, Ahn1 = 0, Ahm0 = 0, Ahm1 = 0;
  u64 Bdl0 = 0, Bln0 = 0, Bln1 = 0, Blm0 = 0, Blm1 = 0;
  u64 Bdh0 = 0, Bdh1 = 0, Bhn0 = 0, Bhn1 = 0, Bhm0 = 0, Bhm1 = 0;
  if (wave == 0) {
    va = vbits[b * 128 + 2 * lane];
    vb2 = vbits[b * 128 + 2 * lane + 1];
    const u64* plo = d2 + (size_t)(0 * 128 + lane) * 6;
    Adl0 = plo[0]; Aln0 = plo[2]; Aln1 = plo[3]; Alm0 = plo[4]; Alm1 = plo[5];
    const u64* phi = d2 + (size_t)(0 * 128 + 64 + lane) * 6;
    Adh0 = phi[0]; Adh1 = phi[1]; Ahn0 = phi[2]; Ahn1 = phi[3];
    Ahm0 = phi[4]; Ahm1 = phi[5];
    const u64* qlo = d2 + (size_t)(1 * 128 + lane) * 6;
    Bdl0 = qlo[0]; Bln0 = qlo[2]; Bln1 = qlo[3]; Blm0 = qlo[4]; Blm1 = qlo[5];
    const u64* qhi = d2 + (size_t)(1 * 128 + 64 + lane) * 6;
    Bdh0 = qhi[0]; Bdh1 = qhi[1]; Bhn0 = qhi[2]; Bhn1 = qhi[3];
    Bhm0 = qhi[4]; Bhm1 = qhi[5];
  }
  // Bg wave state: single-buffered 9 rows x u64x2.
  u64x2 t0{}, t1{}, t2{}, t3{}, t4{}, t5{}, t6{}, t7{}, t8{};
  __syncthreads();  // full drain: zero-row + LDS init visible

  auto sbody = [&](int c, u64& dl0, u64& ln0, u64& ln1, u64& lm0, u64& lm1,
                   u64& dh0, u64& dh1, u64& hn0, u64& hn1, u64& hm0,
                   u64& hm1) {
    u64 rm0 = s_remv[2 * c];
    u64 rm1 = s_remv[2 * c + 1];
    u64 cand0 = readfirstlane64(readlane64(va, c) & ~rm0);
    u64 cand1 = readfirstlane64(readlane64(vb2, c) & ~rm1);
    // 128-bit ballot fixpoint (masks pre-clipped to lower triangle).
    u64 K0 = cand0, K1 = cand1;
    while (true) {
      u64 s0 = __ballot((dl0 & K0) != 0ull);
      u64 s1 = __ballot(((dh0 & K0) | (dh1 & K1)) != 0ull);
      u64 n0 = cand0 & ~s0, n1 = cand1 & ~s1;
      if (n0 == K0 && n1 == K1) break;
      K0 = n0;
      K1 = n1;
    }
    bool klo = (K0 >> lane) & 1, khi = (K1 >> lane) & 1;
    int wd = 2 * c + 2;
    if (klo) {
      if (wd < 128 && ln0) atomicOr(&s_remv[wd], ln0);
      if (wd + 1 < 128 && ln1) atomicOr(&s_remv[wd + 1], ln1);
      if (wd + 2 < 128 && lm0) atomicOr(&s_remv[wd + 2], lm0);
      if (wd + 3 < 128 && lm1) atomicOr(&s_remv[wd + 3], lm1);
    }
    if (khi) {
      if (wd < 128 && hn0) atomicOr(&s_remv[wd], hn0);
      if (wd + 1 < 128 && hn1) atomicOr(&s_remv[wd + 1], hn1);
      if (wd + 2 < 128 && hm0) atomicOr(&s_remv[wd + 2], hm0);
      if (wd + 3 < 128 && hm1) atomicOr(&s_remv[wd + 3], hm1);
    }
    int par = c & 1;
    s_rowlist[par][lane] = NN;
    s_rowlist[par][64 + lane] = NN;
    if (lane < 16) s_rowlist[par][128 + lane] = NN;
    if (klo) {
      int pos = __popcll(K0 & ((1ull << lane) - 1ull));
      s_rowlist[par][pos] = c * 128 + lane;
    }
    if (khi) {
      int pos = __popcll(K0) + __popcll(K1 & ((1ull << lane) - 1ull));
      s_rowlist[par][pos] = c * 128 + 64 + lane;
    }
    if (lane == 0) {
      s_keep[2 * c] = K0;
      s_keep[2 * c + 1] = K1;
    }
    // Prefetch chunk c+2 into this slot (2-body slack; clamp harmless).
    int cp = (c + 2 < 64) ? c + 2 : 63;
    const u64* plo = d2 + (size_t)(cp * 128 + lane) * 6;
    dl0 = plo[0]; ln0 = plo[2]; ln1 = plo[3]; lm0 = plo[4]; lm1 = plo[5];
    const u64* phi = d2 + (size_t)(cp * 128 + 64 + lane) * 6;
    dh0 = phi[0]; dh1 = phi[1]; hn0 = phi[2]; hn1 = phi[3];
    hm0 = phi[4]; hm1 = phi[5];
  };

  auto bgbody = [&](int c) {
    // Consume (rows kept at chunk c-2, loaded at body c-1, start 2c+2).
    u64 ax = t0[0] | t1[0] | t2[0] | t3[0] | t4[0] | t5[0] | t6[0] | t7[0] |
             t8[0];
    u64 ay = t0[1] | t1[1] | t2[1] | t3[1] | t4[1] | t5[1] | t6[1] | t7[1] |
             t8[1];
    int sp = 2 * c + 2;
    int wx = sp + 2 * lane, wy = wx + 1;
    if (wx < 128 && ax) atomicOr(&s_remv[wx], ax);
    if (wy < 128 && ay) atomicOr(&s_remv[wy], ay);
    // Issue rows kept at chunk c-1 (consumed at body c+1, start 2c+4).
    const int* rl = s_rowlist[(c - 1) & 1];  // c=0 -> parity 1 = NN-init
    int base = wave - 1;  // 0..14; stride 15 covers slots 0..134
    int si = 2 * c + 4;
    int w = si + 2 * lane;
    bool wok = w < 128;
    const u64* mw = mb + w;
    const u64* zp = mbz + (size_t)NN * 128;
    int r0 = rl[base], r1 = rl[base + 15], r2 = rl[base + 30],
        r3 = rl[base + 45], r4 = rl[base + 60], r5 = rl[base + 75],
        r6 = rl[base + 90], r7 = rl[base + 105], r8 = rl[base + 120];
    t0 = *(const u64x2*)((wok && r0 != NN) ? mw + (size_t)r0 * 128 : zp);
    t1 = *(const u64x2*)((wok && r1 != NN) ? mw + (size_t)r1 * 128 : zp);
    t2 = *(const u64x2*)((wok && r2 != NN) ? mw + (size_t)r2 * 128 : zp);
    t3 = *(const u64x2*)((wok && r3 != NN) ? mw + (size_t)r3 * 128 : zp);
    t4 = *(const u64x2*)((wok && r4 != NN) ? mw + (size_t)r4 * 128 : zp);
    t5 = *(const u64x2*)((wok && r5 != NN) ? mw + (size_t)r5 * 128 : zp);
    t6 = *(const u64x2*)((wok && r6 != NN) ? mw + (size_t)r6 * 128 : zp);
    t7 = *(const u64x2*)((wok && r7 != NN) ? mw + (size_t)r7 * 128 : zp);
    t8 = *(const u64x2*)((wok && r8 != NN) ? mw + (size_t)r8 * 128 : zp);
  };

  for (int c = 0; c < 64; c += 2) {
    if (wave == 0)
      sbody(c, Adl0, Aln0, Aln1, Alm0, Alm1, Adh0, Adh1, Ahn0, Ahn1, Ahm0,
            Ahm1);
    else
      bgbody(c);
    lbar();
    if (wave == 0)
      sbody(c + 1, Bdl0, Bln0, Bln1, Blm0, Blm1, Bdh0, Bdh1, Bhn0, Bhn1, Bhm0,
            Bhm1);
    else
      bgbody(c + 1);
    lbar();
  }

  if (wave == 0) {
    keepw[b * 128 + 2 * lane] = s_keep[2 * lane];
    keepw[b * 128 + 2 * lane + 1] = s_keep[2 * lane + 1];
  }
}

struct TSet {
  u64x2 t0, t1, t2, t3, t4, t5, t6, t7, t8, t9;
};

// Dense greedy reduce (64-chunk, v13 machinery) — small-ws fallback.
__global__ __launch_bounds__(512) void reduce_dense(
    u64* __restrict__ mask, const u64* __restrict__ vbits,
    const u64* __restrict__ dnm, u64* __restrict__ keepw) {
  int b = blockIdx.x, tid = threadIdx.x;
  int lane = tid & 63, wave = tid >> 6;
  __shared__ u64 s_remv[128];
  __shared__ u64 s_keep[128];
  __shared__ int s_rowlist[2][80];
  u64* mbz = mask + (size_t)b * ROWS * 128;
  const u64* mb = mbz;
  const u64* dn = dnm + (size_t)b * 128 * 4 * 64;

  for (int w = tid; w < 128; w += 512) {
    s_remv[w] = 0ull;
    mbz[(size_t)NN * 128 + w] = 0ull;
  }
  if (tid < 160) s_rowlist[tid / 80][tid % 80] = NN;

  u64 va = 0, vb2 = 0;
  u64 dA = 0, nA = 0, mA = 0, oA = 0, dB = 0, nB = 0, mB = 0, oB = 0;
  u64 dC = 0, nC = 0, mC = 0, oC = 0, dD = 0, nD = 0, mD = 0, oD = 0;
  if (wave == 0) {
    va = vbits[b * 128 + 2 * lane];
    vb2 = vbits[b * 128 + 2 * lane + 1];
    const u64* r0 = dn + lane;
    dA = r0[0]; nA = r0[64]; mA = r0[128]; oA = r0[192];
    const u64* r1 = dn + 4 * 64 + lane;
    dB = r1[0]; nB = r1[64]; mB = r1[128]; oB = r1[192];
  }
  TSet U{}, V{};
  int w0i = 2 * lane;
  __syncthreads();

  auto serial_body = [&](int c, u64 dcur, u64 ncur, u64 mcur, u64 ocur,
                         u64& dnew, u64& nnew, u64& mnew, u64& onew) {
    int cp = (c + 2 < 128) ? (c + 2) : 127;
    const u64* rp = dn + (size_t)cp * 4 * 64 + lane;
    dnew = rp[0]; nnew = rp[64]; mnew = rp[128]; onew = rp[192];
    int par = c & 1;
    u64 rm = s_remv[c];
    u64 vbw = readlane64(par ? vb2 : va, c >> 1);
    u64 cand = readfirstlane64(vbw & ~rm);
    u64 kept = cand;
    while (true) {
      u64 sup = __ballot((dcur & kept) != 0ull);
      u64 nk = cand & ~sup;
      if (nk == kept) break;
      kept = nk;
    }
    bool isk = (kept >> lane) & 1;
    if (c + 1 < 128 && isk && ncur) atomicOr(&s_remv[c + 1], ncur);
    if (c + 2 < 128 && isk && mcur) atomicOr(&s_remv[c + 2], mcur);
    if (c + 3 < 128 && isk && ocur) atomicOr(&s_remv[c + 3], ocur);
    s_rowlist[par][lane] = NN;
    if (isk) {
      int pos = __popcll(kept & ((1ull << lane) - 1ull));
      s_rowlist[par][pos] = c * 64 + lane;
    }
    if (lane == 0) s_keep[c] = kept;
  };

  auto bg_body = [&](int c, TSet& T) {
    u64 ax = T.t0[0] | T.t1[0] | T.t2[0] | T.t3[0] | T.t4[0] | T.t5[0] |
             T.t6[0] | T.t7[0] | T.t8[0] | T.t9[0];
    u64 ay = T.t0[1] | T.t1[1] | T.t2[1] | T.t3[1] | T.t4[1] | T.t5[1] |
             T.t6[1] | T.t7[1] | T.t8[1] | T.t9[1];
    int sc = (c + 1) & ~1;
    int wx = sc + w0i, wy = wx + 1;
    if (wx > c && wx < 128 && ax) atomicOr(&s_remv[wx], ax);
    if (wy > c && wy < 128 && ay) atomicOr(&s_remv[wy], ay);
    const int* rl = s_rowlist[(c - 1) & 1];
    int base = wave - 1;
    int si = (c + 3) & ~1;
    int w = si + w0i;
    bool wok = w < 128;
    const u64* mw = mb + w;
    const u64* zp = mbz + (size_t)NN * 128;
    int r0 = rl[base], r1 = rl[base + 7], r2 = rl[base + 14],
        r3 = rl[base + 21], r4 = rl[base + 28], r5 = rl[base + 35],
        r6 = rl[base + 42], r7 = rl[base + 49], r8 = rl[base + 56],
        r9 = rl[base + 63];
    T.t0 = *(const u64x2*)((wok && r0 != NN) ? mw + (size_t)r0 * 128 : zp);
    T.t1 = *(const u64x2*)((wok && r1 != NN) ? mw + (size_t)r1 * 128 : zp);
    T.t2 = *(const u64x2*)((wok && r2 != NN) ? mw + (size_t)r2 * 128 : zp);
    T.t3 = *(const u64x2*)((wok && r3 != NN) ? mw + (size_t)r3 * 128 : zp);
    T.t4 = *(const u64x2*)((wok && r4 != NN) ? mw + (size_t)r4 * 128 : zp);
    T.t5 = *(const u64x2*)((wok && r5 != NN) ? mw + (size_t)r5 * 128 : zp);
    T.t6 = *(const u64x2*)((wok && r6 != NN) ? mw + (size_t)r6 * 128 : zp);
    T.t7 = *(const u64x2*)((wok && r7 != NN) ? mw + (size_t)r7 * 128 : zp);
    T.t8 = *(const u64x2*)((wok && r8 != NN) ? mw + (size_t)r8 * 128 : zp);
    T.t9 = *(const u64x2*)((wok && r9 != NN) ? mw + (size_t)r9 * 128 : zp);
  };

  for (int c = 0; c < 128; c += 4) {
    if (wave == 0) serial_body(c, dA, nA, mA, oA, dC, nC, mC, oC);
    else bg_body(c, U);
    lbar();
    if (wave == 0) serial_body(c + 1, dB, nB, mB, oB, dD, nD, mD, oD);
    else bg_body(c + 1, V);
    lbar();
    if (wave == 0) serial_body(c + 2, dC, nC, mC, oC, dA, nA, mA, oA);
    else bg_body(c + 2, U);
    lbar();
    if (wave == 0) serial_body(c + 3, dD, nD, mD, oD, dB, nB, mB, oB);
    else bg_body(c + 3, V);
    lbar();
  }

  __syncthreads();
  for (int w = tid; w < 128; w += 512) keepw[b * 128 + w] = s_keep[w];
}

// Scatter keep bits back to original anchor order (parallel epilogue).
__global__ __launch_bounds__(256) void scatter_keep(
    const u64* __restrict__ keepw, const int* __restrict__ order,
    float* __restrict__ keep_out) {
  int b = blockIdx.y;
  int p = blockIdx.x * 256 + threadIdx.x;
  int orig = order[(size_t)b * NN + p];
  keep_out[(size_t)b * NN + orig] =
      ((keepw[b * 128 + (p >> 6)] >> (p & 63)) & 1) ? 1.0f : 0.0f;
}

// Slow-but-correct fallback if d_ws can't hold the mask.
__global__ __launch_bounds__(1024) void nms_fallback(
    const float4* __restrict__ sbox, const u64* __restrict__ vbits,
    const int* __restrict__ order, float* __restrict__ keep_out) {
  int b = blockIdx.x, tid = threadIdx.x;
  __shared__ u64 dead[128];
  __shared__ int s_next;
  __shared__ float4 s_box;
  for (int w = tid; w < 128; w += 1024) dead[w] = ~vbits[b * 128 + w];
  for (int p = tid; p < NN; p += 1024)
    keep_out[(size_t)b * NN + order[(size_t)b * NN + p]] = 0.0f;
  __syncthreads();
  int i = 0;
  while (true) {
    if (tid == 0) {
      int nxt = NN;
      int w = i >> 6;
      u64 live = ~dead[w] & (~0ull << (i & 63));
      while (true) {
        if (live) { nxt = w * 64 + __builtin_ctzll(live); break; }
        if (++w >= 128) break;
        live = ~dead[w];
      }
      s_next = nxt;
      if (nxt < NN) {
        s_box = sbox[(size_t)b * NN + nxt];
        keep_out[(size_t)b * NN + order[(size_t)b * NN + nxt]] = 1.0f;
      }
    }
    __syncthreads();
    i = s_next;
    if (i >= NN) break;
    float4 kb = s_box;
    for (int j = i + 1 + tid; j < NN; j += 1024) {
      if (iou_pair(kb, sbox[(size_t)b * NN + j]) > 0.5f)
        atomicOr(&dead[j >> 6], 1ull << (j & 63));
    }
    __syncthreads();
    i = i + 1;
  }
}

extern "C" void kernel_launch(void* const* d_in, const int* in_sizes, int n_in,
                              void* d_out, int out_size, void* d_ws, size_t ws_size,
                              hipStream_t stream) {
  const float* logits = (const float*)d_in[0];
  const float4* deltas = (const float4*)d_in[1];
  const float4* anchors = (const float4*)d_in[2];
  float* out = (float*)d_out;
  float4* boxes_out = (float4*)(out + OFF_BOXES);
  float* scores_out = out + OFF_SCORES;
  float* labels_out = out + OFF_LABELS;
  float* keep_out = out + OFF_KEEP;
  float* all_out = out + OFF_ALL;

  char* ws = (char*)d_ws;
  u64* keys = (u64*)(ws + WS_KEYS);
  unsigned char* vbyte = (unsigned char*)(ws + WS_VBYTE);
  int* order = (int*)(ws + WS_ORDER);
  float4* sbox = (float4*)(ws + WS_SBOX);
  u64* vbits = (u64*)(ws + WS_VBITS);
  u64* mask = (u64*)(ws + WS_MASK);
  u64* dnm = (u64*)(ws + WS_DNM);
  int* part = (int*)(ws + WS_PART);
  u64* dnm2 = (u64*)(ws + WS_DNM2);
  u64* keepw = (u64*)(ws + WS_KEYS);  // reuses keys region (dead post-rank)

  decode_kernel<<<dim3(NB * NN / 4), dim3(256), 0, stream>>>(
      logits, deltas, anchors, boxes_out, scores_out, labels_out, all_out,
      keys, vbyte, vbits);
  if (ws_size >= WS_TOTAL_128) {
    rank_part_kernel<<<dim3(NN / 256, NSEG, NB), dim3(1024), 0, stream>>>(
        keys, part, dnm, dnm2);
    rank_final_kernel<<<dim3(NN / 256, NB), dim3(256), 0, stream>>>(
        part, (const float4*)boxes_out, vbyte, order, sbox, vbits);
    build_kernel<<<dim3(128, 65, NB), dim3(64), 0, stream>>>(sbox, mask, dnm,
                                                             dnm2);
    reduce128<<<dim3(NB), dim3(1024), 0, stream>>>(mask, vbits, dnm2, keepw);
    scatter_keep<<<dim3(NN / 256, NB), dim3(256), 0, stream>>>(keepw, order,
                                                               keep_out);
  } else if (ws_size >= WS_TOTAL) {
    rank_part_kernel<<<dim3(NN / 256, NSEG, NB), dim3(1024), 0, stream>>>(
        keys, part, dnm, nullptr);
    rank_final_kernel<<<dim3(NN / 256, NB), dim3(256), 0, stream>>>(
        part, (const float4*)boxes_out, vbyte, order, sbox, vbits);
    build_kernel<<<dim3(128, 65, NB), dim3(64), 0, stream>>>(sbox, mask, dnm,
                                                             nullptr);
    reduce_dense<<<dim3(NB), dim3(512), 0, stream>>>(mask, vbits, dnm, keepw);
    scatter_keep<<<dim3(NN / 256, NB), dim3(256), 0, stream>>>(keepw, order,
                                                               keep_out);
  } else if (ws_size >= WS_TOTAL_OLD) {
    rank_kernel<<<dim3(NN / 256, NB), dim3(1024), 0, stream>>>(
        keys, (const float4*)boxes_out, vbyte, order, sbox, vbits, dnm);
    build_kernel<<<dim3(128, 65, NB), dim3(64), 0, stream>>>(sbox, mask, dnm,
                                                             nullptr);
    reduce_dense<<<dim3(NB), dim3(512), 0, stream>>>(mask, vbits, dnm, keepw);
    scatter_keep<<<dim3(NN / 256, NB), dim3(256), 0, stream>>>(keepw, order,
                                                               keep_out);
  } else {
    rank_kernel<<<dim3(NN / 256, NB), dim3(1024), 0, stream>>>(
        keys, (const float4*)boxes_out, vbyte, order, sbox, vbits, dnm);
    nms_fallback<<<dim3(NB), dim3(1024), 0, stream>>>(sbox, vbits, order,
                                                      keep_out);
  }
}